// Round 1
// baseline (114.266 us; speedup 1.0000x reference)
//
#include <hip/hip_runtime.h>
#include <hip/hip_bf16.h>

// Attention cosine-sim + mask + softmax
// query (16,16,1,128) f32, key (16,16,4096,128) f32, mask (16,4096) i32
// out (16,16,4096) f32

constexpr int Bdim = 16, Hdim = 16, Ldim = 4096, Ddim = 128;
constexpr int NTHREADS = 1024;           // 16 waves
constexpr float EPSF = 1e-8f;
constexpr float NEGF = -1000000000.0f;

__global__ __launch_bounds__(NTHREADS, 1) void attn_cos_softmax(
    const float* __restrict__ q,
    const float* __restrict__ k,
    const int* __restrict__ mask,
    float* __restrict__ out)
{
    const int bh = blockIdx.x;           // 0..255
    const int b  = bh >> 4;              // / Hdim
    const float4* qrow = reinterpret_cast<const float4*>(q + (size_t)bh * Ddim);
    const float4* krow = reinterpret_cast<const float4*>(k + (size_t)bh * Ldim * Ddim);
    const int*    mrow = mask + (size_t)b * Ldim;
    float*        orow = out  + (size_t)bh * Ldim;

    __shared__ float s_scores[Ldim];     // 16 KB
    __shared__ float s_redmax[16];
    __shared__ float s_redsum[16];

    const int tid  = threadIdx.x;
    const int g    = tid >> 5;           // 32-lane group id, 0..31
    const int lane = tid & 31;

    // q fragment (float4 per lane covers the 128-elem row across 32 lanes) + ||q||
    float4 qv = qrow[lane];
    float q2 = qv.x*qv.x + qv.y*qv.y + qv.z*qv.z + qv.w*qv.w;
    #pragma unroll
    for (int m = 16; m >= 1; m >>= 1) q2 += __shfl_xor(q2, m);
    const float qn = sqrtf(q2);

    // ---- score phase: each 32-lane group does one row per sub-step, 16 rows batched ----
    constexpr int UNROLL = 16;
    constexpr int ROWS_PER_ITER = 32 * UNROLL;   // 512 rows per block iteration
    #pragma unroll 1
    for (int iter = 0; iter < Ldim / ROWS_PER_ITER; ++iter) {
        const int base = iter * ROWS_PER_ITER + g;
        float4 kv[UNROLL];
        #pragma unroll
        for (int j = 0; j < UNROLL; ++j) {
            kv[j] = krow[(base + j * 32) * (Ddim / 4) + lane];
        }
        #pragma unroll
        for (int j = 0; j < UNROLL; ++j) {
            float dp = qv.x*kv[j].x + qv.y*kv[j].y + qv.z*kv[j].z + qv.w*kv[j].w;
            float k2 = kv[j].x*kv[j].x + kv[j].y*kv[j].y + kv[j].z*kv[j].z + kv[j].w*kv[j].w;
            #pragma unroll
            for (int m = 16; m >= 1; m >>= 1) {
                dp += __shfl_xor(dp, m);
                k2 += __shfl_xor(k2, m);
            }
            if (lane == 0) {
                float denom = fmaxf(qn * sqrtf(k2), EPSF);
                s_scores[base + j * 32] = dp / denom;
            }
        }
    }
    __syncthreads();

    // ---- softmax over L = 4096 (4 elements per thread, in registers) ----
    float sv[4];
    float lmax = -3.0e9f;   // below NEG so an all-masked row matches reference
    #pragma unroll
    for (int i = 0; i < 4; ++i) {
        const int idx = tid + i * NTHREADS;
        float s = s_scores[idx];
        s = (mrow[idx] == 0) ? NEGF : s;
        sv[i] = s;
        lmax = fmaxf(lmax, s);
    }
    #pragma unroll
    for (int m = 32; m >= 1; m >>= 1) lmax = fmaxf(lmax, __shfl_xor(lmax, m));
    if ((tid & 63) == 0) s_redmax[tid >> 6] = lmax;
    __syncthreads();
    float gmax = s_redmax[0];
    #pragma unroll
    for (int i = 1; i < 16; ++i) gmax = fmaxf(gmax, s_redmax[i]);

    float ev[4];
    float lsum = 0.0f;
    #pragma unroll
    for (int i = 0; i < 4; ++i) {
        ev[i] = __expf(sv[i] - gmax);
        lsum += ev[i];
    }
    #pragma unroll
    for (int m = 32; m >= 1; m >>= 1) lsum += __shfl_xor(lsum, m);
    if ((tid & 63) == 0) s_redsum[tid >> 6] = lsum;
    __syncthreads();
    float gsum = 0.0f;
    #pragma unroll
    for (int i = 0; i < 16; ++i) gsum += s_redsum[i];
    const float rinv = 1.0f / gsum;

    #pragma unroll
    for (int i = 0; i < 4; ++i) {
        orow[tid + i * NTHREADS] = ev[i] * rinv;
    }
}

extern "C" void kernel_launch(void* const* d_in, const int* in_sizes, int n_in,
                              void* d_out, int out_size, void* d_ws, size_t ws_size,
                              hipStream_t stream) {
    const float* q    = (const float*)d_in[0];
    const float* k    = (const float*)d_in[1];
    const int*   mask = (const int*)d_in[2];
    float*       out  = (float*)d_out;

    dim3 grid(Bdim * Hdim);
    dim3 block(NTHREADS);
    attn_cos_softmax<<<grid, block, 0, stream>>>(q, k, mask, out);
}

// Round 2
// 104.400 us; speedup vs baseline: 1.0945x; 1.0945x over previous
//
#include <hip/hip_runtime.h>
#include <hip/hip_bf16.h>

// Attention cosine-sim + mask + softmax
// query (16,16,1,128) f32, key (16,16,4096,128) f32, mask (16,4096) i32
// out (16,16,4096) f32

constexpr int Bdim = 16, Hdim = 16, Ldim = 4096, Ddim = 128;
constexpr int NTHREADS = 1024;           // 16 waves
constexpr float EPSF = 1e-8f;
constexpr float NEGF = -1000000000.0f;

// 32-lane-group sum via DPP row ops (VALU pipe, zero DS traffic).
// Valid result in lane 31 of each 32-lane half (lanes 31 and 63 of the wave).
__device__ __forceinline__ float dpp_sum32(float v) {
    v += __int_as_float(__builtin_amdgcn_update_dpp(0, __float_as_int(v), 0x111, 0xf, 0xf, true)); // row_shr:1
    v += __int_as_float(__builtin_amdgcn_update_dpp(0, __float_as_int(v), 0x112, 0xf, 0xf, true)); // row_shr:2
    v += __int_as_float(__builtin_amdgcn_update_dpp(0, __float_as_int(v), 0x114, 0xf, 0xf, true)); // row_shr:4
    v += __int_as_float(__builtin_amdgcn_update_dpp(0, __float_as_int(v), 0x118, 0xf, 0xf, true)); // row_shr:8
    v += __int_as_float(__builtin_amdgcn_update_dpp(0, __float_as_int(v), 0x142, 0xa, 0xf, true)); // row_bcast:15 -> rows 1,3
    return v;
}

__global__ __launch_bounds__(NTHREADS, 1) void attn_cos_softmax(
    const float* __restrict__ q,
    const float* __restrict__ k,
    const int* __restrict__ mask,
    float* __restrict__ out)
{
    const int bh = blockIdx.x;           // 0..255
    const int b  = bh >> 4;              // / Hdim
    const float4* qrow = reinterpret_cast<const float4*>(q + (size_t)bh * Ddim);
    const float4* krow = reinterpret_cast<const float4*>(k + (size_t)bh * Ldim * Ddim);
    const int*    mrow = mask + (size_t)b * Ldim;
    float*        orow = out  + (size_t)bh * Ldim;

    __shared__ float s_scores[Ldim];     // 16 KB
    __shared__ float s_redmax[16];
    __shared__ float s_redsum[16];

    const int tid  = threadIdx.x;
    const int g    = tid >> 5;           // 32-lane group id, 0..31
    const int lane = tid & 31;
    const bool writer = (lane == 31);    // DPP reduction lands in lane 31 of each group

    // q fragment (float4 per lane covers the 128-elem row across 32 lanes) + ||q||
    float4 qv = qrow[lane];
    float q2 = qv.x*qv.x + qv.y*qv.y + qv.z*qv.z + qv.w*qv.w;
    q2 = dpp_sum32(q2);                  // valid on writer lane only — that's all we need
    const float qn = sqrtf(q2);

    // ---- score phase: each 32-lane group does one row per sub-step, 16 rows batched ----
    constexpr int UNROLL = 16;
    constexpr int ROWS_PER_ITER = 32 * UNROLL;   // 512 rows per block iteration
    #pragma unroll 1
    for (int iter = 0; iter < Ldim / ROWS_PER_ITER; ++iter) {
        const int base = iter * ROWS_PER_ITER + g;
        float4 kv[UNROLL];
        #pragma unroll
        for (int j = 0; j < UNROLL; ++j) {
            kv[j] = krow[(base + j * 32) * (Ddim / 4) + lane];
        }
        #pragma unroll
        for (int j = 0; j < UNROLL; ++j) {
            float dp = kv[j].x*qv.x + kv[j].y*qv.y + kv[j].z*qv.z + kv[j].w*qv.w;
            float k2 = kv[j].x*kv[j].x + kv[j].y*kv[j].y + kv[j].z*kv[j].z + kv[j].w*kv[j].w;
            dp = dpp_sum32(dp);
            k2 = dpp_sum32(k2);
            if (writer) {
                float denom = fmaxf(qn * sqrtf(k2), EPSF);
                s_scores[base + j * 32] = dp / denom;
            }
        }
    }
    __syncthreads();

    // ---- softmax over L = 4096 (4 elements per thread, in registers) ----
    float sv[4];
    float lmax = -3.0e9f;   // below NEG so an all-masked row matches reference
    #pragma unroll
    for (int i = 0; i < 4; ++i) {
        const int idx = tid + i * NTHREADS;
        float s = s_scores[idx];
        s = (mrow[idx] == 0) ? NEGF : s;
        sv[i] = s;
        lmax = fmaxf(lmax, s);
    }
    #pragma unroll
    for (int m = 32; m >= 1; m >>= 1) lmax = fmaxf(lmax, __shfl_xor(lmax, m));
    if ((tid & 63) == 0) s_redmax[tid >> 6] = lmax;
    __syncthreads();
    float gmax = s_redmax[0];
    #pragma unroll
    for (int i = 1; i < 16; ++i) gmax = fmaxf(gmax, s_redmax[i]);

    float ev[4];
    float lsum = 0.0f;
    #pragma unroll
    for (int i = 0; i < 4; ++i) {
        ev[i] = __expf(sv[i] - gmax);
        lsum += ev[i];
    }
    #pragma unroll
    for (int m = 32; m >= 1; m >>= 1) lsum += __shfl_xor(lsum, m);
    if ((tid & 63) == 0) s_redsum[tid >> 6] = lsum;
    __syncthreads();
    float gsum = 0.0f;
    #pragma unroll
    for (int i = 0; i < 16; ++i) gsum += s_redsum[i];
    const float rinv = 1.0f / gsum;

    #pragma unroll
    for (int i = 0; i < 4; ++i) {
        orow[tid + i * NTHREADS] = ev[i] * rinv;
    }
}

extern "C" void kernel_launch(void* const* d_in, const int* in_sizes, int n_in,
                              void* d_out, int out_size, void* d_ws, size_t ws_size,
                              hipStream_t stream) {
    const float* q    = (const float*)d_in[0];
    const float* k    = (const float*)d_in[1];
    const int*   mask = (const int*)d_in[2];
    float*       out  = (float*)d_out;

    dim3 grid(Bdim * Hdim);
    dim3 block(NTHREADS);
    attn_cos_softmax<<<grid, block, 0, stream>>>(q, k, mask, out);
}